// Round 2
// baseline (1903.258 us; speedup 1.0000x reference)
//
#include <hip/hip_runtime.h>
#include <cstdint>
#include <cstddef>

#define T_DIM 4096
#define B_DIM 32
#define D_DIM 512
#define H_DIM 256
#define G_DIM 1024  // 4*H

typedef _Float16 h2 __attribute__((ext_vector_type(2)));
typedef _Float16 h8 __attribute__((ext_vector_type(8)));
typedef float f4 __attribute__((ext_vector_type(4)));

// ---------------------------------------------------------------------------
// Kernel A: per-batch segment extraction. A segment starts at t==0 or where
// reset[t,b]==1 (state is zeroed entering that step). Block b compacts the
// ordered start list for batch column b.
// ---------------------------------------------------------------------------
__global__ void seg_build_kernel(const int* __restrict__ reset,
                                 unsigned* __restrict__ starts,
                                 unsigned* __restrict__ segcnt) {
  __shared__ unsigned cnts[256];
  __shared__ unsigned offs[256];
  const int b = blockIdx.x;
  const int tid = threadIdx.x;
  const int t0 = tid * 16;
  unsigned c = 0;
  for (int e = 0; e < 16; ++e) {
    int t = t0 + e;
    bool pred = (t == 0) || (reset[t * B_DIM + b] != 0);
    c += pred ? 1u : 0u;
  }
  cnts[tid] = c;
  __syncthreads();
  if (tid == 0) {
    unsigned run = 0;
    for (int i = 0; i < 256; ++i) { unsigned v = cnts[i]; offs[i] = run; run += v; }
    segcnt[b] = run;
  }
  __syncthreads();
  unsigned o = (unsigned)b * 4096u + offs[tid];
  for (int e = 0; e < 16; ++e) {
    int t = t0 + e;
    bool pred = (t == 0) || (reset[t * B_DIM + b] != 0);
    if (pred) { starts[o++] = (unsigned)t; }
  }
}

// ---------------------------------------------------------------------------
// Kernel B: xw = x @ W_ih^T + b_ih + b_hh, output f16 [T*B, 1024].
// (unchanged from R0; ~550us, VALU-bound on f32->f16 staging cvt — next target)
// ---------------------------------------------------------------------------
#define BM 128
#define BN 128
#define BK 32

__global__ __launch_bounds__(256) void xw_gemm_kernel(
    const float* __restrict__ X, const float* __restrict__ Wih,
    const float* __restrict__ bih, const float* __restrict__ bhh,
    _Float16* __restrict__ xw) {
  __shared__ _Float16 As[BM * BK];
  __shared__ _Float16 Bs[BN * BK];
  const int tid = threadIdx.x;
  const int lane = tid & 63;
  const int wave = tid >> 6;
  const size_t m0 = (size_t)blockIdx.y * BM;
  const int n0 = blockIdx.x * BN;
  const int wm = (wave & 1) * 64;   // wave tile 64x64
  const int wn = (wave >> 1) * 64;
  const int q = lane >> 4;          // quad 0..3
  const int r = lane & 15;

  f4 acc[4][4];
#pragma unroll
  for (int i = 0; i < 4; ++i) {
#pragma unroll
    for (int j = 0; j < 4; ++j) { f4 z = {0.f, 0.f, 0.f, 0.f}; acc[i][j] = z; }
  }

  const int srow = tid >> 1;
  const int kh = (tid & 1) * 16;

  for (int k0 = 0; k0 < D_DIM; k0 += BK) {
    const float* ax = X + (m0 + (size_t)srow) * D_DIM + k0 + kh;
    const float* bx = Wih + ((size_t)(n0 + srow)) * D_DIM + k0 + kh;
    f4 a0 = *(const f4*)(ax);
    f4 a1 = *(const f4*)(ax + 4);
    f4 a2 = *(const f4*)(ax + 8);
    f4 a3 = *(const f4*)(ax + 12);
    f4 b0 = *(const f4*)(bx);
    f4 b1 = *(const f4*)(bx + 4);
    f4 b2 = *(const f4*)(bx + 8);
    f4 b3 = *(const f4*)(bx + 12);
    h8 ha0 = {(_Float16)a0.x, (_Float16)a0.y, (_Float16)a0.z, (_Float16)a0.w,
              (_Float16)a1.x, (_Float16)a1.y, (_Float16)a1.z, (_Float16)a1.w};
    h8 ha1 = {(_Float16)a2.x, (_Float16)a2.y, (_Float16)a2.z, (_Float16)a2.w,
              (_Float16)a3.x, (_Float16)a3.y, (_Float16)a3.z, (_Float16)a3.w};
    h8 hb0 = {(_Float16)b0.x, (_Float16)b0.y, (_Float16)b0.z, (_Float16)b0.w,
              (_Float16)b1.x, (_Float16)b1.y, (_Float16)b1.z, (_Float16)b1.w};
    h8 hb1 = {(_Float16)b2.x, (_Float16)b2.y, (_Float16)b2.z, (_Float16)b2.w,
              (_Float16)b3.x, (_Float16)b3.y, (_Float16)b3.z, (_Float16)b3.w};
    *(h8*)(As + srow * BK + kh) = ha0;
    *(h8*)(As + srow * BK + kh + 8) = ha1;
    *(h8*)(Bs + srow * BK + kh) = hb0;
    *(h8*)(Bs + srow * BK + kh + 8) = hb1;
    __syncthreads();

    h8 af[4], bf[4];
#pragma unroll
    for (int mi = 0; mi < 4; ++mi)
      af[mi] = *(const h8*)(As + (wm + mi * 16 + r) * BK + q * 8);
#pragma unroll
    for (int ni = 0; ni < 4; ++ni)
      bf[ni] = *(const h8*)(Bs + (wn + ni * 16 + r) * BK + q * 8);
#pragma unroll
    for (int mi = 0; mi < 4; ++mi)
#pragma unroll
      for (int ni = 0; ni < 4; ++ni)
        acc[mi][ni] = __builtin_amdgcn_mfma_f32_16x16x32_f16(af[mi], bf[ni], acc[mi][ni], 0, 0, 0);
    __syncthreads();
  }

  // C/D layout: col(n) = lane&15, row(m) = (lane>>4)*4 + reg  [m89/m91 verified]
#pragma unroll
  for (int mi = 0; mi < 4; ++mi) {
#pragma unroll
    for (int ni = 0; ni < 4; ++ni) {
      int n = n0 + wn + ni * 16 + r;
      float bias = bih[n] + bhh[n];
#pragma unroll
      for (int reg = 0; reg < 4; ++reg) {
        size_t m = m0 + (size_t)(wm + mi * 16 + q * 4 + reg);
        xw[m * G_DIM + n] = (_Float16)(acc[mi][ni][reg] + bias);
      }
    }
  }
}

// ---------------------------------------------------------------------------
// Kernel C: segment-parallel LSTM scan. 256 blocks x 1024 threads, 1 block/CU.
// R1 fix: W_hh rows k=0..191 in 24 INDIVIDUALLY-NAMED h8 registers (96 VGPRs,
// no array -> no scratch demotion) + __launch_bounds__(1024,4) -> 128 VGPR cap
// (16 waves/CU = 4 waves/EU; 512/4 = 128). k=192..255 stays in LDS (128 KB).
// Gate nonlinearities moved pre-barrier onto all 1024 threads.
// ---------------------------------------------------------------------------
__device__ __forceinline__ float sigmf(float x) { return 1.f / (1.f + __expf(-x)); }
__device__ __forceinline__ float tanhf_(float x) {
  float e = __expf(-2.f * fabsf(x));
  float r = (1.f - e) / (1.f + e);
  return copysignf(r, x);
}
__device__ __forceinline__ float dot8(h8 w, h8 h, float acc) {
  acc = __builtin_amdgcn_fdot2(__builtin_shufflevector(w, w, 0, 1),
                               __builtin_shufflevector(h, h, 0, 1), acc, false);
  acc = __builtin_amdgcn_fdot2(__builtin_shufflevector(w, w, 2, 3),
                               __builtin_shufflevector(h, h, 2, 3), acc, false);
  acc = __builtin_amdgcn_fdot2(__builtin_shufflevector(w, w, 4, 5),
                               __builtin_shufflevector(h, h, 4, 5), acc, false);
  acc = __builtin_amdgcn_fdot2(__builtin_shufflevector(w, w, 6, 7),
                               __builtin_shufflevector(h, h, 6, 7), acc, false);
  return acc;
}
__device__ __forceinline__ h8 cvt8(const float* p) {
  f4 v0 = *(const f4*)p;
  f4 v1 = *(const f4*)(p + 4);
  h8 w = {(_Float16)v0.x, (_Float16)v0.y, (_Float16)v0.z, (_Float16)v0.w,
          (_Float16)v1.x, (_Float16)v1.y, (_Float16)v1.z, (_Float16)v1.w};
  return w;
}

__global__ __launch_bounds__(1024, 4) void lstm_scan_kernel(
    const _Float16* __restrict__ xw,
    const float* __restrict__ Whh,
    const float* __restrict__ Wproj,
    const float* __restrict__ bproj,
    const unsigned* __restrict__ starts,
    const unsigned* __restrict__ segcnt,
    float* __restrict__ out) {
  __shared__ __align__(16) _Float16 wlds[8 * G_DIM * 8];  // 128 KB
  __shared__ float act[G_DIM];
  __shared__ __align__(16) _Float16 hbuf[H_DIM];
  __shared__ float partial[4];

  const int tid = threadIdx.x;
  const int b = blockIdx.x & 31;
  const int sub = blockIdx.x >> 5;

  const float* wrow = Whh + (size_t)tid * H_DIM;
  // 24 named h8 regs = 96 VGPRs; named scalars cannot be demoted to scratch.
  h8 wr0  = cvt8(wrow + 0),   wr1  = cvt8(wrow + 8),   wr2  = cvt8(wrow + 16);
  h8 wr3  = cvt8(wrow + 24),  wr4  = cvt8(wrow + 32),  wr5  = cvt8(wrow + 40);
  h8 wr6  = cvt8(wrow + 48),  wr7  = cvt8(wrow + 56),  wr8  = cvt8(wrow + 64);
  h8 wr9  = cvt8(wrow + 72),  wr10 = cvt8(wrow + 80),  wr11 = cvt8(wrow + 88);
  h8 wr12 = cvt8(wrow + 96),  wr13 = cvt8(wrow + 104), wr14 = cvt8(wrow + 112);
  h8 wr15 = cvt8(wrow + 120), wr16 = cvt8(wrow + 128), wr17 = cvt8(wrow + 136);
  h8 wr18 = cvt8(wrow + 144), wr19 = cvt8(wrow + 152), wr20 = cvt8(wrow + 160);
  h8 wr21 = cvt8(wrow + 168), wr22 = cvt8(wrow + 176), wr23 = cvt8(wrow + 184);
#pragma unroll
  for (int j = 0; j < 8; ++j) {
    *(h8*)(wlds + ((size_t)j * G_DIM + tid) * 8) = cvt8(wrow + 192 + j * 8);
  }
  const float wp = (tid < H_DIM) ? Wproj[tid] : 0.f;
  const float bp = bproj[0];
  const int gate = tid >> 8;  // 0=i 1=f 2=g 3=o (wave-uniform)
  __syncthreads();

  const h8* hb8 = (const h8*)hbuf;
  const h8* wl8 = (const h8*)wlds;
  const unsigned nseg = segcnt[b];

  for (unsigned s = sub; s < nseg; s += 8) {
    const unsigned t0 = starts[b * 4096u + s];
    const unsigned t1 = (s + 1 < nseg) ? starts[b * 4096u + s + 1] : (unsigned)T_DIM;
    float cst = 0.f;
    for (unsigned t = t0; t < t1; ++t) {
      float xv = (float)xw[((size_t)t * B_DIM + b) * G_DIM + tid];
      float accv;
      if (t == t0) {
        // first step of a segment: h == 0, recurrent term vanishes
        accv = xv;
      } else {
        float a0 = 0.f, a1 = 0.f, a2 = 0.f, a3 = 0.f;
        a0 = dot8(wr0,  hb8[0],  a0);  a1 = dot8(wr1,  hb8[1],  a1);
        a2 = dot8(wr2,  hb8[2],  a2);  a3 = dot8(wr3,  hb8[3],  a3);
        a0 = dot8(wr4,  hb8[4],  a0);  a1 = dot8(wr5,  hb8[5],  a1);
        a2 = dot8(wr6,  hb8[6],  a2);  a3 = dot8(wr7,  hb8[7],  a3);
        a0 = dot8(wr8,  hb8[8],  a0);  a1 = dot8(wr9,  hb8[9],  a1);
        a2 = dot8(wr10, hb8[10], a2);  a3 = dot8(wr11, hb8[11], a3);
        a0 = dot8(wr12, hb8[12], a0);  a1 = dot8(wr13, hb8[13], a1);
        a2 = dot8(wr14, hb8[14], a2);  a3 = dot8(wr15, hb8[15], a3);
        a0 = dot8(wr16, hb8[16], a0);  a1 = dot8(wr17, hb8[17], a1);
        a2 = dot8(wr18, hb8[18], a2);  a3 = dot8(wr19, hb8[19], a3);
        a0 = dot8(wr20, hb8[20], a0);  a1 = dot8(wr21, hb8[21], a1);
        a2 = dot8(wr22, hb8[22], a2);  a3 = dot8(wr23, hb8[23], a3);
        a0 = dot8(wl8[0 * G_DIM + tid], hb8[24], a0);
        a1 = dot8(wl8[1 * G_DIM + tid], hb8[25], a1);
        a2 = dot8(wl8[2 * G_DIM + tid], hb8[26], a2);
        a3 = dot8(wl8[3 * G_DIM + tid], hb8[27], a3);
        a0 = dot8(wl8[4 * G_DIM + tid], hb8[28], a0);
        a1 = dot8(wl8[5 * G_DIM + tid], hb8[29], a1);
        a2 = dot8(wl8[6 * G_DIM + tid], hb8[30], a2);
        a3 = dot8(wl8[7 * G_DIM + tid], hb8[31], a3);
        accv = ((a0 + a1) + (a2 + a3)) + xv;
      }
      // per-gate nonlinearity on all 1024 threads (wave-uniform branch)
      act[tid] = (gate == 2) ? tanhf_(accv) : sigmf(accv);
      __syncthreads();
      if (tid < H_DIM) {
        float vi = act[tid];
        float vf = act[tid + 256];
        float vg = act[tid + 512];
        float vo = act[tid + 768];
        cst = vf * cst + vi * vg;
        float h = vo * tanhf_(cst);
        hbuf[tid] = (_Float16)h;
        float p = h * wp;
        p += __shfl_down(p, 32);
        p += __shfl_down(p, 16);
        p += __shfl_down(p, 8);
        p += __shfl_down(p, 4);
        p += __shfl_down(p, 2);
        p += __shfl_down(p, 1);
        if ((tid & 63) == 0) partial[tid >> 6] = p;
      }
      __syncthreads();
      if (tid == 0) {
        out[(size_t)t * B_DIM + b] = partial[0] + partial[1] + partial[2] + partial[3] + bp;
      }
      // safe: next act/partial writes are ordered behind the NEXT barrier,
      // which thread 0 only reaches after this read.
    }
  }
}

// ---------------------------------------------------------------------------
extern "C" void kernel_launch(void* const* d_in, const int* in_sizes, int n_in,
                              void* d_out, int out_size, void* d_ws, size_t ws_size,
                              hipStream_t stream) {
  const float* x = (const float*)d_in[0];
  const int* reset = (const int*)d_in[1];
  const float* Wih = (const float*)d_in[2];
  const float* Whh = (const float*)d_in[3];
  const float* bih = (const float*)d_in[4];
  const float* bhh = (const float*)d_in[5];
  const float* Wproj = (const float*)d_in[6];
  const float* bproj = (const float*)d_in[7];
  float* out = (float*)d_out;

  char* ws = (char*)d_ws;
  _Float16* xw = (_Float16*)ws;                              // 268435456 B
  unsigned* starts = (unsigned*)(ws + 268435456ULL);         // 524288 B
  unsigned* segcnt = (unsigned*)(ws + 268959744ULL);         // 128 B

  hipLaunchKernelGGL(seg_build_kernel, dim3(32), dim3(256), 0, stream,
                     reset, starts, segcnt);
  hipLaunchKernelGGL(xw_gemm_kernel, dim3(8, 1024), dim3(256), 0, stream,
                     x, Wih, bih, bhh, xw);
  hipLaunchKernelGGL(lstm_scan_kernel, dim3(256), dim3(1024), 0, stream,
                     xw, Whh, Wproj, bproj, starts, segcnt, out);
}

// Round 3
// 1446.955 us; speedup vs baseline: 1.3154x; 1.3154x over previous
//
#include <hip/hip_runtime.h>
#include <cstdint>
#include <cstddef>

#define T_DIM 4096
#define B_DIM 32
#define D_DIM 512
#define H_DIM 256
#define G_DIM 1024  // 4*H
#define HSTR 264    // padded H-row stride in f16 elems (2-way LDS aliasing = free)

typedef _Float16 h8 __attribute__((ext_vector_type(8)));
typedef float f4 __attribute__((ext_vector_type(4)));

// ---------------------------------------------------------------------------
// Kernel A: per-batch segment extraction (unchanged, verified R0/R1).
// ---------------------------------------------------------------------------
__global__ void seg_build_kernel(const int* __restrict__ reset,
                                 unsigned* __restrict__ starts,
                                 unsigned* __restrict__ segcnt) {
  __shared__ unsigned cnts[256];
  __shared__ unsigned offs[256];
  const int b = blockIdx.x;
  const int tid = threadIdx.x;
  const int t0 = tid * 16;
  unsigned c = 0;
  for (int e = 0; e < 16; ++e) {
    int t = t0 + e;
    bool pred = (t == 0) || (reset[t * B_DIM + b] != 0);
    c += pred ? 1u : 0u;
  }
  cnts[tid] = c;
  __syncthreads();
  if (tid == 0) {
    unsigned run = 0;
    for (int i = 0; i < 256; ++i) { unsigned v = cnts[i]; offs[i] = run; run += v; }
    segcnt[b] = run;
  }
  __syncthreads();
  unsigned o = (unsigned)b * 4096u + offs[tid];
  for (int e = 0; e < 16; ++e) {
    int t = t0 + e;
    bool pred = (t == 0) || (reset[t * B_DIM + b] != 0);
    if (pred) { starts[o++] = (unsigned)t; }
  }
}

// ---------------------------------------------------------------------------
// Kernel A2: flatten per-batch segment lists into one global queue.
// flat[i] = (t0 | b<<16, t1). meta[0]=pull counter (init 0), meta[1]=nseg.
// ---------------------------------------------------------------------------
__global__ void seg_flat_kernel(const unsigned* __restrict__ starts,
                                const unsigned* __restrict__ segcnt,
                                uint2* __restrict__ flat,
                                unsigned* __restrict__ meta) {
  __shared__ unsigned offs;
  const int b = blockIdx.x;
  const int tid = threadIdx.x;
  if (tid == 0) {
    unsigned o = 0;
    for (int i = 0; i < b; ++i) o += segcnt[i];
    offs = o;
    if (b == 31) meta[1] = o + segcnt[31];
    if (b == 0) meta[0] = 0u;
  }
  __syncthreads();
  const unsigned cnt = segcnt[b];
  const unsigned off = offs;
  for (unsigned s = tid; s < cnt; s += 256) {
    unsigned t0 = starts[b * 4096u + s];
    unsigned t1 = (s + 1 < cnt) ? starts[b * 4096u + s + 1] : 4096u;
    flat[off + s] = make_uint2(t0 | ((unsigned)b << 16), t1);
  }
}

// ---------------------------------------------------------------------------
// Kernel A3: pack W_hh (f32 [1024][256]) into f16 MFMA B-fragment order.
// Frag (nt 0..63, ks 0..7, lane 0..63): 8 f16 = W[nt*16+(l&15)][ks*32+(l>>4)*8 + j]
// ---------------------------------------------------------------------------
__global__ void wpack_kernel(const float* __restrict__ Whh,
                             _Float16* __restrict__ wpack) {
  int gid = blockIdx.x * 256 + threadIdx.x;  // 0..32767
  int nt = gid >> 9;
  int rem = gid & 511;
  int ks = rem >> 6;
  int l = rem & 63;
  int n = nt * 16 + (l & 15);
  int k = ks * 32 + (l >> 4) * 8;
  const float* src = Whh + (size_t)n * H_DIM + k;
  f4 v0 = *(const f4*)src;
  f4 v1 = *(const f4*)(src + 4);
  h8 wv = {(_Float16)v0.x, (_Float16)v0.y, (_Float16)v0.z, (_Float16)v0.w,
           (_Float16)v1.x, (_Float16)v1.y, (_Float16)v1.z, (_Float16)v1.w};
  *(h8*)(wpack + (size_t)gid * 8) = wv;
}

// ---------------------------------------------------------------------------
// Kernel B: xw = x @ W_ih^T + b_ih + b_hh, output f16 [T*B, 1024]. (unchanged)
// ---------------------------------------------------------------------------
#define BM 128
#define BN 128
#define BK 32

__global__ __launch_bounds__(256) void xw_gemm_kernel(
    const float* __restrict__ X, const float* __restrict__ Wih,
    const float* __restrict__ bih, const float* __restrict__ bhh,
    _Float16* __restrict__ xw) {
  __shared__ _Float16 As[BM * BK];
  __shared__ _Float16 Bs[BN * BK];
  const int tid = threadIdx.x;
  const int lane = tid & 63;
  const int wave = tid >> 6;
  const size_t m0 = (size_t)blockIdx.y * BM;
  const int n0 = blockIdx.x * BN;
  const int wm = (wave & 1) * 64;
  const int wn = (wave >> 1) * 64;
  const int q = lane >> 4;
  const int r = lane & 15;

  f4 acc[4][4];
#pragma unroll
  for (int i = 0; i < 4; ++i)
#pragma unroll
    for (int j = 0; j < 4; ++j) { f4 z = {0.f, 0.f, 0.f, 0.f}; acc[i][j] = z; }

  const int srow = tid >> 1;
  const int kh = (tid & 1) * 16;

  for (int k0 = 0; k0 < D_DIM; k0 += BK) {
    const float* ax = X + (m0 + (size_t)srow) * D_DIM + k0 + kh;
    const float* bx = Wih + ((size_t)(n0 + srow)) * D_DIM + k0 + kh;
    f4 a0 = *(const f4*)(ax);
    f4 a1 = *(const f4*)(ax + 4);
    f4 a2 = *(const f4*)(ax + 8);
    f4 a3 = *(const f4*)(ax + 12);
    f4 b0 = *(const f4*)(bx);
    f4 b1 = *(const f4*)(bx + 4);
    f4 b2 = *(const f4*)(bx + 8);
    f4 b3 = *(const f4*)(bx + 12);
    h8 ha0 = {(_Float16)a0.x, (_Float16)a0.y, (_Float16)a0.z, (_Float16)a0.w,
              (_Float16)a1.x, (_Float16)a1.y, (_Float16)a1.z, (_Float16)a1.w};
    h8 ha1 = {(_Float16)a2.x, (_Float16)a2.y, (_Float16)a2.z, (_Float16)a2.w,
              (_Float16)a3.x, (_Float16)a3.y, (_Float16)a3.z, (_Float16)a3.w};
    h8 hb0 = {(_Float16)b0.x, (_Float16)b0.y, (_Float16)b0.z, (_Float16)b0.w,
              (_Float16)b1.x, (_Float16)b1.y, (_Float16)b1.z, (_Float16)b1.w};
    h8 hb1 = {(_Float16)b2.x, (_Float16)b2.y, (_Float16)b2.z, (_Float16)b2.w,
              (_Float16)b3.x, (_Float16)b3.y, (_Float16)b3.z, (_Float16)b3.w};
    *(h8*)(As + srow * BK + kh) = ha0;
    *(h8*)(As + srow * BK + kh + 8) = ha1;
    *(h8*)(Bs + srow * BK + kh) = hb0;
    *(h8*)(Bs + srow * BK + kh + 8) = hb1;
    __syncthreads();

    h8 af[4], bf[4];
#pragma unroll
    for (int mi = 0; mi < 4; ++mi)
      af[mi] = *(const h8*)(As + (wm + mi * 16 + r) * BK + q * 8);
#pragma unroll
    for (int ni = 0; ni < 4; ++ni)
      bf[ni] = *(const h8*)(Bs + (wn + ni * 16 + r) * BK + q * 8);
#pragma unroll
    for (int mi = 0; mi < 4; ++mi)
#pragma unroll
      for (int ni = 0; ni < 4; ++ni)
        acc[mi][ni] = __builtin_amdgcn_mfma_f32_16x16x32_f16(af[mi], bf[ni], acc[mi][ni], 0, 0, 0);
    __syncthreads();
  }

#pragma unroll
  for (int mi = 0; mi < 4; ++mi) {
#pragma unroll
    for (int ni = 0; ni < 4; ++ni) {
      int n = n0 + wn + ni * 16 + r;
      float bias = bih[n] + bhh[n];
#pragma unroll
      for (int reg = 0; reg < 4; ++reg) {
        size_t m = m0 + (size_t)(wm + mi * 16 + q * 4 + reg);
        xw[m * G_DIM + n] = (_Float16)(acc[mi][ni][reg] + bias);
      }
    }
  }
}

// ---------------------------------------------------------------------------
// Kernel C: MFMA-lockstep segment-parallel LSTM scan.
// 256 blocks x 1024 thr (1/CU, LDS-forced). 32 segments lockstep per block;
// per super-step: gates[32x1024] = H[32x256] @ Whh^T via mfma_16x16x32_f16.
// Wave w owns n-tiles {w, w+16, w+32, w+48} = gates i,f,g,o for hh in
// [16w,16w+16) -> state update fully wave-local; c in registers (f32 x8).
// W residency: ks0 in regs (16 VGPR), ks1-2 in LDS (128 KB), ks3-7 from L2.
// ---------------------------------------------------------------------------
__device__ __forceinline__ float sigmf(float x) { return 1.f / (1.f + __expf(-x)); }
__device__ __forceinline__ float tanhf_(float x) {
  float e = __expf(-2.f * fabsf(x));
  float r = (1.f - e) / (1.f + e);
  return copysignf(r, x);
}
__device__ __forceinline__ f4 MF(h8 a, h8 b, f4 c) {
  return __builtin_amdgcn_mfma_f32_16x16x32_f16(a, b, c, 0, 0, 0);
}

#define WPK(g, ks) ((const h8*)(wpack + (((size_t)(((g)*16 + w) * 8 + (ks))) * 64 + l) * 8))
#define WLD(g, ks2) (*(const h8*)(Wlds + ((((ks2)*64) + ((g)*16 + w)) * 64 + l) * 8))
#define ARD(mt, ks) (*(const h8*)(Hbuf + (16*(mt) + r16) * HSTR + (ks)*32 + q*8))

#define MFMA8(B0, B1, B2, B3, KS)                          \
  a0 = ARD(0, KS); a1 = ARD(1, KS);                        \
  acc00 = MF(a0, B0, acc00); acc10 = MF(a1, B0, acc10);    \
  acc01 = MF(a0, B1, acc01); acc11 = MF(a1, B1, acc11);    \
  acc02 = MF(a0, B2, acc02); acc12 = MF(a1, B2, acc12);    \
  acc03 = MF(a0, B3, acc03); acc13 = MF(a1, B3, acc13);

#define XWADD(ACC, RB, G) {                                          \
  int nb = (G)*512 + nbase2;                                         \
  f4 xv;                                                             \
  xv.x = (float)*(const _Float16*)(xwc + RB.x + nb);                 \
  xv.y = (float)*(const _Float16*)(xwc + RB.y + nb);                 \
  xv.z = (float)*(const _Float16*)(xwc + RB.z + nb);                 \
  xv.w = (float)*(const _Float16*)(xwc + RB.w + nb);                 \
  ACC += xv; }

#define CONTROL_STEP do {                                                    \
  int m = tid;                                                               \
  if (alivef[m]) {                                                           \
    unsigned oi = outix[m];                                                  \
    if (oi != 0xFFFFFFFFu) {                                                 \
      float s = bp;                                                          \
      _Pragma("unroll") for (int ww = 0; ww < 16; ++ww) s += pbuf[ww][m];    \
      out[oi] = s;                                                           \
    }                                                                        \
    int t = tcur[m] + 1;                                                     \
    if (t < tend[m]) {                                                       \
      tcur[m] = t; keepm[m] = 1.f;                                           \
      unsigned row = (unsigned)t * 32u + (unsigned)bcol[m];                  \
      trowB[m] = row * 2048u; outix[m] = row;                                \
    } else {                                                                 \
      unsigned idx = atomicAdd(ctr, 1u);                                     \
      if (idx < nseg) {                                                      \
        uint2 sg = flat[idx];                                                \
        int t0s = (int)(sg.x & 0xFFFFu); int bb = (int)(sg.x >> 16);         \
        tcur[m] = t0s; tend[m] = (int)sg.y; bcol[m] = bb; keepm[m] = 0.f;    \
        unsigned row = (unsigned)t0s * 32u + (unsigned)bb;                   \
        trowB[m] = row * 2048u; outix[m] = row;                              \
        h8 zz = {0,0,0,0,0,0,0,0};                                           \
        _Pragma("unroll") for (int i2 = 0; i2 < 33; ++i2)                    \
          *(h8*)(Hbuf + (size_t)m * HSTR + i2 * 8) = zz;                     \
      } else {                                                               \
        alivef[m] = 0; outix[m] = 0xFFFFFFFFu; trowB[m] = 0;                 \
        keepm[m] = 0.f;                                                      \
      }                                                                      \
    }                                                                        \
  }                                                                          \
} while (0)

__global__ __launch_bounds__(1024, 4) void lstm_scan_mfma(
    const _Float16* __restrict__ xw,
    const _Float16* __restrict__ wpack,
    const float* __restrict__ Wproj,
    const float* __restrict__ bproj,
    const uint2* __restrict__ flat,
    unsigned* __restrict__ meta,
    float* __restrict__ out) {
  __shared__ __align__(16) _Float16 Wlds[2 * 64 * 64 * 8];  // 128 KB (ks 1,2)
  __shared__ __align__(16) _Float16 Hbuf[32 * HSTR];        // 16.9 KB
  __shared__ __align__(16) float pbuf[16][32];              // 2 KB
  __shared__ __align__(16) unsigned trowB[32];
  __shared__ __align__(16) float keepm[32];
  __shared__ unsigned outix[32];
  __shared__ int tcur[32], tend[32], bcol[32], alivef[32];

  const int tid = threadIdx.x;
  const int l = tid & 63;
  const int w = tid >> 6;
  const int q = l >> 4;
  const int r16 = l & 15;
  const int hh = 16 * w + r16;
  const int nbase2 = hh * 2;
  const char* xwc = (const char*)xw;
  unsigned* ctr = meta;
  const unsigned nseg = meta[1];

  // init: LDS weights (global ksteps 1,2), zero Hbuf
  for (int it = 0; it < 8; ++it) {
    int idx = it * 1024 + tid;
    int ks2 = idx >> 12;
    int nt = (idx >> 6) & 63;
    int ll = idx & 63;
    *(h8*)(Wlds + (size_t)idx * 8) =
        *(const h8*)(wpack + (((size_t)(nt * 8 + ks2 + 1)) * 64 + ll) * 8);
  }
  for (int i = tid; i < 32 * HSTR / 8; i += 1024) {
    h8 z = {0,0,0,0,0,0,0,0};
    *(h8*)(Hbuf + (size_t)i * 8) = z;
  }
  // register weights: kstep 0, gates 0..3
  h8 wb0 = *WPK(0, 0), wb1 = *WPK(1, 0), wb2 = *WPK(2, 0), wb3 = *WPK(3, 0);
  const float wpv = Wproj[hh];
  const float bp = bproj[0];
  if (tid < 32) {
    alivef[tid] = 1; tcur[tid] = 0; tend[tid] = 0; bcol[tid] = 0;
    outix[tid] = 0xFFFFFFFFu; trowB[tid] = 0; keepm[tid] = 0.f;
  }
  float cst[8] = {0, 0, 0, 0, 0, 0, 0, 0};
  float pr[8];
  __syncthreads();
  if (tid < 32) CONTROL_STEP;  // initial segment pulls (outix invalid -> no out-write)
  int nalive = __syncthreads_count(tid < 32 ? alivef[tid] : 0);

  while (nalive > 0) {
    f4 z4 = {0.f, 0.f, 0.f, 0.f};
    f4 acc00 = z4, acc01 = z4, acc02 = z4, acc03 = z4;
    f4 acc10 = z4, acc11 = z4, acc12 = z4, acc13 = z4;
    h8 a0, a1;
    // stream prefetch ks3, ks4
    h8 s0 = *WPK(0, 3), s1 = *WPK(1, 3), s2 = *WPK(2, 3), s3 = *WPK(3, 3);
    MFMA8(wb0, wb1, wb2, wb3, 0)
    h8 u0 = *WPK(0, 4), u1 = *WPK(1, 4), u2 = *WPK(2, 4), u3 = *WPK(3, 4);
    { h8 b0 = WLD(0, 0), b1 = WLD(1, 0), b2 = WLD(2, 0), b3 = WLD(3, 0);
      MFMA8(b0, b1, b2, b3, 1) }
    { h8 b0 = WLD(0, 1), b1 = WLD(1, 1), b2 = WLD(2, 1), b3 = WLD(3, 1);
      MFMA8(b0, b1, b2, b3, 2) }
    MFMA8(s0, s1, s2, s3, 3)
    s0 = *WPK(0, 5); s1 = *WPK(1, 5); s2 = *WPK(2, 5); s3 = *WPK(3, 5);
    MFMA8(u0, u1, u2, u3, 4)
    u0 = *WPK(0, 6); u1 = *WPK(1, 6); u2 = *WPK(2, 6); u3 = *WPK(3, 6);
    MFMA8(s0, s1, s2, s3, 5)
    s0 = *WPK(0, 7); s1 = *WPK(1, 7); s2 = *WPK(2, 7); s3 = *WPK(3, 7);
    MFMA8(u0, u1, u2, u3, 6)
    MFMA8(s0, s1, s2, s3, 7)

    __syncthreads();  // B0: all Hbuf reads complete before h-writes below

    // xw add (per-lane rows m = 16*mt + q*4 + r)
    uint4 rb0 = *(const uint4*)&trowB[q * 4];
    uint4 rb1 = *(const uint4*)&trowB[16 + q * 4];
    XWADD(acc00, rb0, 0) XWADD(acc01, rb0, 1) XWADD(acc02, rb0, 2) XWADD(acc03, rb0, 3)
    XWADD(acc10, rb1, 0) XWADD(acc11, rb1, 1) XWADD(acc12, rb1, 2) XWADD(acc13, rb1, 3)

    // nonlinearity + state update + h-write + projection partial (wave-local)
    f4 kp0 = *(const f4*)&keepm[q * 4];
    f4 kp1 = *(const f4*)&keepm[16 + q * 4];
#pragma unroll
    for (int r = 0; r < 4; ++r) {
      float gi = sigmf(acc00[r]);
      float gf = sigmf(acc01[r]);
      float gg = tanhf_(acc02[r]);
      float go = sigmf(acc03[r]);
      float cn = gf * (cst[r] * kp0[r]) + gi * gg;
      cst[r] = cn;
      float hv = go * tanhf_(cn);
      Hbuf[(q * 4 + r) * HSTR + hh] = (_Float16)hv;
      pr[r] = hv * wpv;
    }
#pragma unroll
    for (int r = 0; r < 4; ++r) {
      float gi = sigmf(acc10[r]);
      float gf = sigmf(acc11[r]);
      float gg = tanhf_(acc12[r]);
      float go = sigmf(acc13[r]);
      float cn = gf * (cst[4 + r] * kp1[r]) + gi * gg;
      cst[4 + r] = cn;
      float hv = go * tanhf_(cn);
      Hbuf[(16 + q * 4 + r) * HSTR + hh] = (_Float16)hv;
      pr[4 + r] = hv * wpv;
    }
    // reduce projection over the 16 hh-lanes (bits 0..3 of lane id)
#pragma unroll
    for (int j = 0; j < 8; ++j) {
      pr[j] += __shfl_xor(pr[j], 1);
      pr[j] += __shfl_xor(pr[j], 2);
      pr[j] += __shfl_xor(pr[j], 4);
      pr[j] += __shfl_xor(pr[j], 8);
    }
    if (r16 == 0) {
#pragma unroll
      for (int j = 0; j < 8; ++j)
        pbuf[w][16 * (j >> 2) + q * 4 + (j & 3)] = pr[j];
    }

    __syncthreads();  // B1: pbuf/Hbuf writes complete before control reads/zeroes
    if (tid < 32) CONTROL_STEP;
    nalive = __syncthreads_count(tid < 32 ? alivef[tid] : 0);
  }
}

// ---------------------------------------------------------------------------
extern "C" void kernel_launch(void* const* d_in, const int* in_sizes, int n_in,
                              void* d_out, int out_size, void* d_ws, size_t ws_size,
                              hipStream_t stream) {
  const float* x = (const float*)d_in[0];
  const int* reset = (const int*)d_in[1];
  const float* Wih = (const float*)d_in[2];
  const float* Whh = (const float*)d_in[3];
  const float* bih = (const float*)d_in[4];
  const float* bhh = (const float*)d_in[5];
  const float* Wproj = (const float*)d_in[6];
  const float* bproj = (const float*)d_in[7];
  float* out = (float*)d_out;

  char* ws = (char*)d_ws;
  _Float16* xw = (_Float16*)ws;                           // 268435456 B
  unsigned* starts = (unsigned*)(ws + 268435456ULL);      // 524288 B
  unsigned* segcnt = (unsigned*)(ws + 268959744ULL);      // 128 B
  uint2* flat = (uint2*)(ws + 268959872ULL);              // 1048576 B
  _Float16* wpack = (_Float16*)(ws + 270008448ULL);       // 524288 B
  unsigned* meta = (unsigned*)(ws + 270532736ULL);        // 8 B

  hipLaunchKernelGGL(seg_build_kernel, dim3(32), dim3(256), 0, stream,
                     reset, starts, segcnt);
  hipLaunchKernelGGL(seg_flat_kernel, dim3(32), dim3(256), 0, stream,
                     starts, segcnt, flat, meta);
  hipLaunchKernelGGL(wpack_kernel, dim3(128), dim3(256), 0, stream,
                     Whh, wpack);
  hipLaunchKernelGGL(xw_gemm_kernel, dim3(8, 1024), dim3(256), 0, stream,
                     x, Wih, bih, bhh, xw);
  hipLaunchKernelGGL(lstm_scan_mfma, dim3(256), dim3(1024), 0, stream,
                     xw, wpack, Wproj, bproj, flat, meta, out);
}